// Round 1
// baseline (17504.042 us; speedup 1.0000x reference)
//
#include <hip/hip_runtime.h>
#include <math.h>

#define BB 8
#define TT 50
#define AA 1444      // A*A
#define CC 64
#define HH 1024
#define G4 4096      // 4*H
#define INX 92416    // A*A*C
#define IND 93860    // INX + AA

__device__ __forceinline__ float sigf(float x) { return 1.0f / (1.0f + __expf(-x)); }

// ---------------------------------------------------------------------------
// K0: zero the recurrent state
__global__ void k_init(float* __restrict__ h, float* __restrict__ c,
                       float* __restrict__ att) {
    int i = blockIdx.x * 256 + threadIdx.x;
    if (i < BB * HH) { h[i] = 0.f; c[i] = 0.f; }
    if (i < BB * AA) att[i] = 0.f;
}

// ---------------------------------------------------------------------------
// K1: gates[b][g] = b_ih[g] + b_hh[g]
//                 + sum_k W_ih[g][k] * inp[k][b]   (inp = [x_t*att, m_t])
//                 + sum_j W_hh[g][j] * h[b][j]
// One block computes 8 rows (g0..g0+7) for all 8 batches, full reduction.
__global__ __launch_bounds__(256, 2)
void k_gates(const float* __restrict__ x,       // tensors (B,T,A,A,C)
             const float* __restrict__ masks,   // (B,T,AA)
             const float* __restrict__ Wih,     // (4H, IN)
             const float* __restrict__ Whh,     // (4H, H)
             const float* __restrict__ bih, const float* __restrict__ bhh,
             const float* __restrict__ h,       // (B,H)
             const float* __restrict__ att,     // (B,AA)
             float* __restrict__ gates,         // (B,4H)
             int t) {
    __shared__ float att_s[BB * AA];
    const int tid = threadIdx.x;
    for (int i = tid; i < BB * AA; i += 256) att_s[i] = att[i];
    __syncthreads();

    const int g0 = blockIdx.x * 8;
    float acc[8][8];
#pragma unroll
    for (int r = 0; r < 8; ++r)
#pragma unroll
        for (int b = 0; b < 8; ++b) acc[r][b] = 0.f;

    // ---- x part (attention-gated), k in [0, INX)
    const float* xb = x + (size_t)t * INX;  // + b*T*INX + k
    for (int k = tid; k < INX; k += 256) {
        const int ij = k >> 6;
        float xa[8];
#pragma unroll
        for (int b = 0; b < 8; ++b)
            xa[b] = xb[(size_t)b * TT * INX + k] * att_s[b * AA + ij];
#pragma unroll
        for (int r = 0; r < 8; ++r) {
            float w = __builtin_nontemporal_load(&Wih[(size_t)(g0 + r) * IND + k]);
#pragma unroll
            for (int b = 0; b < 8; ++b) acc[r][b] = fmaf(w, xa[b], acc[r][b]);
        }
    }

    // ---- mask part, k in [0, AA)
    const float* mb = masks + (size_t)t * AA;  // + b*T*AA + k
    for (int k = tid; k < AA; k += 256) {
        float mv[8];
#pragma unroll
        for (int b = 0; b < 8; ++b) mv[b] = mb[(size_t)b * TT * AA + k];
#pragma unroll
        for (int r = 0; r < 8; ++r) {
            float w = __builtin_nontemporal_load(&Wih[(size_t)(g0 + r) * IND + INX + k]);
#pragma unroll
            for (int b = 0; b < 8; ++b) acc[r][b] = fmaf(w, mv[b], acc[r][b]);
        }
    }

    // ---- recurrent part, j in [0, H)
    for (int j = tid; j < HH; j += 256) {
        float hv[8];
#pragma unroll
        for (int b = 0; b < 8; ++b) hv[b] = h[b * HH + j];
#pragma unroll
        for (int r = 0; r < 8; ++r) {
            float w = Whh[(size_t)(g0 + r) * HH + j];
#pragma unroll
            for (int b = 0; b < 8; ++b) acc[r][b] = fmaf(w, hv[b], acc[r][b]);
        }
    }

    // ---- fixed-order reduction: wave shuffle, then cross-wave via LDS
#pragma unroll
    for (int r = 0; r < 8; ++r)
#pragma unroll
        for (int b = 0; b < 8; ++b) {
            float v = acc[r][b];
            for (int off = 32; off; off >>= 1) v += __shfl_down(v, off, 64);
            acc[r][b] = v;
        }
    __shared__ float red[4][8][8];
    const int wave = tid >> 6, lane = tid & 63;
    if (lane == 0) {
#pragma unroll
        for (int r = 0; r < 8; ++r)
#pragma unroll
            for (int b = 0; b < 8; ++b) red[wave][r][b] = acc[r][b];
    }
    __syncthreads();
    if (tid < 64) {
        const int r = tid >> 3, b = tid & 7;
        const int g = g0 + r;
        float v = red[0][r][b] + red[1][r][b] + red[2][r][b] + red[3][r][b];
        gates[b * G4 + g] = v + bih[g] + bhh[g];
    }
}

// ---------------------------------------------------------------------------
// K2: LSTM pointwise cell update
__global__ void k_cell(const float* __restrict__ gates, float* __restrict__ c,
                       float* __restrict__ h, float* __restrict__ hrelu) {
    int idx = blockIdx.x * 256 + threadIdx.x;  // 0..8191
    if (idx >= BB * HH) return;
    const int b = idx >> 10, j = idx & (HH - 1);
    const float* gb = gates + b * G4;
    float ig = sigf(gb[j]);
    float fg = sigf(gb[HH + j]);
    float gg = tanhf(gb[2 * HH + j]);
    float og = sigf(gb[3 * HH + j]);
    float cn = fg * c[idx] + ig * gg;
    float hn = og * tanhf(cn);
    c[idx] = cn;
    h[idx] = hn;
    hrelu[idx] = fmaxf(hn, 0.f);
}

// ---------------------------------------------------------------------------
// K3: att_new = sigmoid(hrelu @ W_att.T + b_att); out_t = sigmoid(hrelu @ W_out.T + b_out)
// One wave per (matrix, row), all 8 batches.
__global__ __launch_bounds__(256)
void k_attout(const float* __restrict__ hrelu,
              const float* __restrict__ Watt, const float* __restrict__ batt,
              const float* __restrict__ Wout, const float* __restrict__ bout,
              float* __restrict__ att, float* __restrict__ out, int t) {
    const int wid = blockIdx.x * 4 + (threadIdx.x >> 6);
    const int lane = threadIdx.x & 63;
    if (wid >= 2 * AA) return;
    const bool isAtt = wid < AA;
    const int row = isAtt ? wid : wid - AA;
    const float* W = isAtt ? Watt : Wout;

    float acc[8];
#pragma unroll
    for (int b = 0; b < 8; ++b) acc[b] = 0.f;
    for (int j = lane; j < HH; j += 64) {
        float w = W[(size_t)row * HH + j];
#pragma unroll
        for (int b = 0; b < 8; ++b) acc[b] = fmaf(w, hrelu[b * HH + j], acc[b]);
    }
#pragma unroll
    for (int b = 0; b < 8; ++b) {
        float v = acc[b];
        for (int off = 32; off; off >>= 1) v += __shfl_xor(v, off, 64);
        acc[b] = v;
    }
    if (lane < 8) {
        const int b = lane;
        if (isAtt)
            att[b * AA + row] = sigf(acc[b] + batt[row]);
        else
            out[((size_t)b * TT + t) * AA + row] = sigf(acc[b] + bout[row]);
    }
}

// ---------------------------------------------------------------------------
extern "C" void kernel_launch(void* const* d_in, const int* in_sizes, int n_in,
                              void* d_out, int out_size, void* d_ws, size_t ws_size,
                              hipStream_t stream) {
    const float* tensors = (const float*)d_in[0];
    const float* masks   = (const float*)d_in[1];
    const float* Wih     = (const float*)d_in[2];
    const float* Whh     = (const float*)d_in[3];
    const float* bih     = (const float*)d_in[4];
    const float* bhh     = (const float*)d_in[5];
    const float* Watt    = (const float*)d_in[6];
    const float* batt    = (const float*)d_in[7];
    const float* Wout    = (const float*)d_in[8];
    const float* bout    = (const float*)d_in[9];
    float* out = (float*)d_out;

    float* ws    = (float*)d_ws;
    float* h     = ws;               // 8192
    float* c     = h + BB * HH;      // 8192
    float* hrelu = c + BB * HH;      // 8192
    float* att   = hrelu + BB * HH;  // 11552
    float* gates = att + BB * AA;    // 32768

    k_init<<<46, 256, 0, stream>>>(h, c, att);
    for (int t = 0; t < TT; ++t) {
        k_gates<<<512, 256, 0, stream>>>(tensors, masks, Wih, Whh, bih, bhh, h,
                                         att, gates, t);
        k_cell<<<32, 256, 0, stream>>>(gates, c, h, hrelu);
        k_attout<<<722, 256, 0, stream>>>(hrelu, Watt, batt, Wout, bout, att,
                                          out, t);
    }
}

// Round 4
// 13896.713 us; speedup vs baseline: 1.2596x; 1.2596x over previous
//
#include <hip/hip_runtime.h>
#include <math.h>

#define BB 8
#define TT 50
#define AA 1444      // A*A
#define CC 64
#define HH 1024
#define G4 4096      // 4*H
#define INX 92416    // A*A*C
#define IND 93860    // INX + AA
#define INDP 93864   // IND rounded up to multiple of 8 (bf16 row stride)

typedef unsigned int u32;
typedef unsigned short u16;
typedef u32 u32x4 __attribute__((ext_vector_type(4)));  // native vector for nontemporal builtin

__device__ __forceinline__ float sigf(float x) { return 1.0f / (1.0f + expf(-x)); }

__device__ __forceinline__ u16 f2bf_rtne(float f) {
    u32 u = __float_as_uint(f);
    u = (u + 0x7FFFu + ((u >> 16) & 1u)) >> 16;
    return (u16)u;
}

// ---------------------------------------------------------------------------
// K0: zero the recurrent state
__global__ void k_init(float* __restrict__ h, float* __restrict__ c,
                       float* __restrict__ att) {
    int i = blockIdx.x * 256 + threadIdx.x;
    if (i < BB * HH) { h[i] = 0.f; c[i] = 0.f; }
    if (i < BB * AA) att[i] = 0.f;
}

// ---------------------------------------------------------------------------
// K-cvt: W_ih f32 -> bf16 (RTNE), row stride padded to INDP for alignment.
__global__ __launch_bounds__(256)
void k_cvt(const float* __restrict__ W, u16* __restrict__ Wb) {
    const int g = blockIdx.x;
    const float* src = W + (size_t)g * IND;
    u16* dst = Wb + (size_t)g * INDP;
    for (int k = threadIdx.x * 8; k + 8 <= IND; k += 2048) {
        float4 a = *(const float4*)(src + k);
        float4 b = *(const float4*)(src + k + 4);
        union { u16 s[8]; u32x4 v; } pk;
        pk.s[0] = f2bf_rtne(a.x); pk.s[1] = f2bf_rtne(a.y);
        pk.s[2] = f2bf_rtne(a.z); pk.s[3] = f2bf_rtne(a.w);
        pk.s[4] = f2bf_rtne(b.x); pk.s[5] = f2bf_rtne(b.y);
        pk.s[6] = f2bf_rtne(b.z); pk.s[7] = f2bf_rtne(b.w);
        *(u32x4*)(dst + k) = pk.v;
    }
    const int tail = IND & ~7;  // 93856
    if (threadIdx.x < IND - tail) {
        int k = tail + threadIdx.x;
        dst[k] = f2bf_rtne(src[k]);
    }
}

// ---------------------------------------------------------------------------
// K1: fused gates + LSTM cell. Block bx owns hidden units j0=2*bx, j0+1 and
// all four gates for them: row r in [0,8): gate=r>>1, j=j0+(r&1),
// W-row = gate*H + j. Epilogue computes c/h/hrelu for its 2 units x 8 batches.
// h is double-buffered (hin read by all blocks, hout written per-block).
__global__ __launch_bounds__(256, 2)
void k_gates_cell(const float* __restrict__ x,       // tensors (B,T,A,A,C)
                  const float* __restrict__ masks,   // (B,T,AA)
                  const u16* __restrict__ Wb,        // bf16 (4H, INDP)
                  const float* __restrict__ Whh,     // (4H, H)
                  const float* __restrict__ bih, const float* __restrict__ bhh,
                  const float* __restrict__ hin,     // (B,H)
                  const float* __restrict__ att,     // (B,AA)
                  float* __restrict__ c, float* __restrict__ hout,
                  float* __restrict__ hrelu, int t) {
    __shared__ float att_s[BB * AA];
    const int tid = threadIdx.x;
    for (int i = tid; i < BB * AA; i += 256) att_s[i] = att[i];
    __syncthreads();

    const int j0 = blockIdx.x * 2;
    const u16* wrow[8];
#pragma unroll
    for (int r = 0; r < 8; ++r)
        wrow[r] = Wb + (size_t)((r >> 1) * HH + j0 + (r & 1)) * INDP;

    float acc[8][8];
#pragma unroll
    for (int r = 0; r < 8; ++r)
#pragma unroll
        for (int b = 0; b < 8; ++b) acc[r][b] = 0.f;

    // ---- x part (attention-gated), k in [0, INX), 8 per thread per iter
    const float* xb = x + (size_t)t * INX;
    for (int k0 = tid * 8; k0 < INX; k0 += 2048) {
        const int ij = k0 >> 6;
        float xa[8][8];
#pragma unroll
        for (int b = 0; b < 8; ++b) {
            const float* xp = xb + (size_t)b * TT * INX + k0;
            float4 x0 = *(const float4*)(xp);
            float4 x1 = *(const float4*)(xp + 4);
            const float am = att_s[b * AA + ij];
            xa[b][0] = x0.x * am; xa[b][1] = x0.y * am;
            xa[b][2] = x0.z * am; xa[b][3] = x0.w * am;
            xa[b][4] = x1.x * am; xa[b][5] = x1.y * am;
            xa[b][6] = x1.z * am; xa[b][7] = x1.w * am;
        }
#pragma unroll
        for (int r = 0; r < 8; ++r) {
            u32x4 wv = __builtin_nontemporal_load((const u32x4*)(wrow[r] + k0));
#pragma unroll
            for (int q = 0; q < 4; ++q) {
                const u32 wq = wv[q];
                const float wlo = __uint_as_float(wq << 16);
                const float whi = __uint_as_float(wq & 0xFFFF0000u);
#pragma unroll
                for (int b = 0; b < 8; ++b)
                    acc[r][b] = fmaf(wlo, xa[b][2 * q], acc[r][b]);
#pragma unroll
                for (int b = 0; b < 8; ++b)
                    acc[r][b] = fmaf(whi, xa[b][2 * q + 1], acc[r][b]);
            }
        }
    }

    // ---- mask part, k in [0, AA), scalar bf16 (only 1.5% of the row)
    const float* mb = masks + (size_t)t * AA;
    for (int k = tid; k < AA; k += 256) {
        float mv[8];
#pragma unroll
        for (int b = 0; b < 8; ++b) mv[b] = mb[(size_t)b * TT * AA + k];
#pragma unroll
        for (int r = 0; r < 8; ++r) {
            const float w = __uint_as_float((u32)wrow[r][INX + k] << 16);
#pragma unroll
            for (int b = 0; b < 8; ++b) acc[r][b] = fmaf(w, mv[b], acc[r][b]);
        }
    }

    // ---- recurrent part (f32, L2/L3-resident)
    for (int j = tid; j < HH; j += 256) {
        float hv[8];
#pragma unroll
        for (int b = 0; b < 8; ++b) hv[b] = hin[b * HH + j];
#pragma unroll
        for (int r = 0; r < 8; ++r) {
            const float w = Whh[(size_t)((r >> 1) * HH + j0 + (r & 1)) * HH + j];
#pragma unroll
            for (int b = 0; b < 8; ++b) acc[r][b] = fmaf(w, hv[b], acc[r][b]);
        }
    }

    // ---- fixed-order reduction: wave shuffle, then cross-wave via LDS
#pragma unroll
    for (int r = 0; r < 8; ++r)
#pragma unroll
        for (int b = 0; b < 8; ++b) {
            float v = acc[r][b];
            for (int off = 32; off; off >>= 1) v += __shfl_down(v, off, 64);
            acc[r][b] = v;
        }
    __shared__ float red[4][8][8];
    __shared__ float gfin[8][8];
    const int wave = tid >> 6, lane = tid & 63;
    if (lane == 0) {
#pragma unroll
        for (int r = 0; r < 8; ++r)
#pragma unroll
            for (int b = 0; b < 8; ++b) red[wave][r][b] = acc[r][b];
    }
    __syncthreads();
    if (tid < 64) {
        const int r = tid >> 3, b = tid & 7;
        const int row = (r >> 1) * HH + j0 + (r & 1);
        gfin[r][b] = red[0][r][b] + red[1][r][b] + red[2][r][b] + red[3][r][b]
                   + bih[row] + bhh[row];
    }
    __syncthreads();
    if (tid < 16) {
        const int jl = tid >> 3, b = tid & 7;  // jl in {0,1}
        const int j = j0 + jl;
        const float ig = sigf(gfin[0 + jl][b]);
        const float fg = sigf(gfin[2 + jl][b]);
        const float gg = tanhf(gfin[4 + jl][b]);
        const float og = sigf(gfin[6 + jl][b]);
        const int idx = b * HH + j;
        const float cn = fg * c[idx] + ig * gg;
        const float hn = og * tanhf(cn);
        c[idx] = cn;
        hout[idx] = hn;
        hrelu[idx] = fmaxf(hn, 0.f);
    }
}

// ---------------------------------------------------------------------------
// K3: att_new = sigmoid(hrelu @ W_att.T + b_att); out_t = sigmoid(hrelu @ W_out.T + b_out)
__global__ __launch_bounds__(256)
void k_attout(const float* __restrict__ hrelu,
              const float* __restrict__ Watt, const float* __restrict__ batt,
              const float* __restrict__ Wout, const float* __restrict__ bout,
              float* __restrict__ att, float* __restrict__ out, int t) {
    const int wid = blockIdx.x * 4 + (threadIdx.x >> 6);
    const int lane = threadIdx.x & 63;
    if (wid >= 2 * AA) return;
    const bool isAtt = wid < AA;
    const int row = isAtt ? wid : wid - AA;
    const float* W = isAtt ? Watt : Wout;

    float acc[8];
#pragma unroll
    for (int b = 0; b < 8; ++b) acc[b] = 0.f;
    for (int j = lane; j < HH; j += 64) {
        const float w = W[(size_t)row * HH + j];
#pragma unroll
        for (int b = 0; b < 8; ++b) acc[b] = fmaf(w, hrelu[b * HH + j], acc[b]);
    }
#pragma unroll
    for (int b = 0; b < 8; ++b) {
        float v = acc[b];
        for (int off = 32; off; off >>= 1) v += __shfl_xor(v, off, 64);
        acc[b] = v;
    }
    if (lane < 8) {
        const int b = lane;
        if (isAtt)
            att[b * AA + row] = sigf(acc[b] + batt[row]);
        else
            out[((size_t)b * TT + t) * AA + row] = sigf(acc[b] + bout[row]);
    }
}

// ---------------------------------------------------------------------------
// Fallback f32 path (validated in round 1) if ws is too small for bf16 W.
__global__ __launch_bounds__(256, 2)
void k_gates_f32(const float* __restrict__ x, const float* __restrict__ masks,
                 const float* __restrict__ Wih, const float* __restrict__ Whh,
                 const float* __restrict__ bih, const float* __restrict__ bhh,
                 const float* __restrict__ h, const float* __restrict__ att,
                 float* __restrict__ gates, int t) {
    __shared__ float att_s[BB * AA];
    const int tid = threadIdx.x;
    for (int i = tid; i < BB * AA; i += 256) att_s[i] = att[i];
    __syncthreads();
    const int g0 = blockIdx.x * 8;
    float acc[8][8];
#pragma unroll
    for (int r = 0; r < 8; ++r)
#pragma unroll
        for (int b = 0; b < 8; ++b) acc[r][b] = 0.f;
    const float* xb = x + (size_t)t * INX;
    for (int k = tid; k < INX; k += 256) {
        const int ij = k >> 6;
        float xa[8];
#pragma unroll
        for (int b = 0; b < 8; ++b)
            xa[b] = xb[(size_t)b * TT * INX + k] * att_s[b * AA + ij];
#pragma unroll
        for (int r = 0; r < 8; ++r) {
            float w = __builtin_nontemporal_load(&Wih[(size_t)(g0 + r) * IND + k]);
#pragma unroll
            for (int b = 0; b < 8; ++b) acc[r][b] = fmaf(w, xa[b], acc[r][b]);
        }
    }
    const float* mb = masks + (size_t)t * AA;
    for (int k = tid; k < AA; k += 256) {
        float mv[8];
#pragma unroll
        for (int b = 0; b < 8; ++b) mv[b] = mb[(size_t)b * TT * AA + k];
#pragma unroll
        for (int r = 0; r < 8; ++r) {
            float w = __builtin_nontemporal_load(&Wih[(size_t)(g0 + r) * IND + INX + k]);
#pragma unroll
            for (int b = 0; b < 8; ++b) acc[r][b] = fmaf(w, mv[b], acc[r][b]);
        }
    }
    for (int j = tid; j < HH; j += 256) {
        float hv[8];
#pragma unroll
        for (int b = 0; b < 8; ++b) hv[b] = h[b * HH + j];
#pragma unroll
        for (int r = 0; r < 8; ++r) {
            float w = Whh[(size_t)(g0 + r) * HH + j];
#pragma unroll
            for (int b = 0; b < 8; ++b) acc[r][b] = fmaf(w, hv[b], acc[r][b]);
        }
    }
#pragma unroll
    for (int r = 0; r < 8; ++r)
#pragma unroll
        for (int b = 0; b < 8; ++b) {
            float v = acc[r][b];
            for (int off = 32; off; off >>= 1) v += __shfl_down(v, off, 64);
            acc[r][b] = v;
        }
    __shared__ float red[4][8][8];
    const int wave = tid >> 6, lane = tid & 63;
    if (lane == 0) {
#pragma unroll
        for (int r = 0; r < 8; ++r)
#pragma unroll
            for (int b = 0; b < 8; ++b) red[wave][r][b] = acc[r][b];
    }
    __syncthreads();
    if (tid < 64) {
        const int r = tid >> 3, b = tid & 7;
        const int g = g0 + r;
        float v = red[0][r][b] + red[1][r][b] + red[2][r][b] + red[3][r][b];
        gates[b * G4 + g] = v + bih[g] + bhh[g];
    }
}

__global__ void k_cell(const float* __restrict__ gates, float* __restrict__ c,
                       float* __restrict__ h, float* __restrict__ hrelu) {
    int idx = blockIdx.x * 256 + threadIdx.x;
    if (idx >= BB * HH) return;
    const int b = idx >> 10, j = idx & (HH - 1);
    const float* gb = gates + b * G4;
    float ig = sigf(gb[j]);
    float fg = sigf(gb[HH + j]);
    float gg = tanhf(gb[2 * HH + j]);
    float og = sigf(gb[3 * HH + j]);
    float cn = fg * c[idx] + ig * gg;
    float hn = og * tanhf(cn);
    c[idx] = cn;
    h[idx] = hn;
    hrelu[idx] = fmaxf(hn, 0.f);
}

// ---------------------------------------------------------------------------
extern "C" void kernel_launch(void* const* d_in, const int* in_sizes, int n_in,
                              void* d_out, int out_size, void* d_ws, size_t ws_size,
                              hipStream_t stream) {
    const float* tensors = (const float*)d_in[0];
    const float* masks   = (const float*)d_in[1];
    const float* Wih     = (const float*)d_in[2];
    const float* Whh     = (const float*)d_in[3];
    const float* bih     = (const float*)d_in[4];
    const float* bhh     = (const float*)d_in[5];
    const float* Watt    = (const float*)d_in[6];
    const float* batt    = (const float*)d_in[7];
    const float* Wout    = (const float*)d_in[8];
    const float* bout    = (const float*)d_in[9];
    float* out = (float*)d_out;

    float* ws    = (float*)d_ws;
    float* h0    = ws;                // 8192
    float* h1    = h0 + BB * HH;      // 8192
    float* c     = h1 + BB * HH;      // 8192
    float* hrelu = c + BB * HH;       // 8192
    float* att   = hrelu + BB * HH;   // 11552
    float* gates = att + BB * AA;     // 32768 (fallback only)
    u16*   Wb    = (u16*)(gates + BB * G4);  // bf16 weights, 16B-aligned

    const size_t need = (size_t)(4 * BB * HH + BB * AA + BB * G4) * 4
                      + (size_t)G4 * INDP * 2;
    const bool bf16path = ws_size >= need;

    k_init<<<46, 256, 0, stream>>>(h0, c, att);
    if (bf16path) {
        k_cvt<<<G4, 256, 0, stream>>>(Wih, Wb);
        for (int t = 0; t < TT; ++t) {
            const float* hin = (t & 1) ? h1 : h0;
            float* hout = (t & 1) ? h0 : h1;
            k_gates_cell<<<512, 256, 0, stream>>>(tensors, masks, Wb, Whh, bih,
                                                  bhh, hin, att, c, hout, hrelu, t);
            k_attout<<<722, 256, 0, stream>>>(hrelu, Watt, batt, Wout, bout,
                                              att, out, t);
        }
    } else {
        for (int t = 0; t < TT; ++t) {
            k_gates_f32<<<512, 256, 0, stream>>>(tensors, masks, Wih, Whh, bih,
                                                 bhh, h0, att, gates, t);
            k_cell<<<32, 256, 0, stream>>>(gates, c, h0, hrelu);
            k_attout<<<722, 256, 0, stream>>>(hrelu, Watt, batt, Wout, bout,
                                              att, out, t);
        }
    }
}

// Round 5
// 9040.352 us; speedup vs baseline: 1.9362x; 1.5372x over previous
//
#include <hip/hip_runtime.h>
#include <math.h>

#define BB 8
#define TT 50
#define AA 1444      // A*A
#define HH 1024
#define G4 4096      // 4*H
#define INX 92416    // A*A*C  (= 2888 * 32, exact)
#define IND 93860    // INX + AA
#define INDP 93888   // IND padded to multiple of 32 (MFMA K-blocks)
#define NKB 2934     // INDP / 32
#define KPW 367      // ceil(NKB / 8) K-blocks per wave in k_gemm

typedef unsigned int u32;
typedef unsigned short u16;
typedef u32 u32x4 __attribute__((ext_vector_type(4)));
typedef short s16x8 __attribute__((ext_vector_type(8)));   // 8 bf16 (4 VGPRs)
typedef float f32x4 __attribute__((ext_vector_type(4)));

__device__ __forceinline__ float sigf(float x) { return 1.0f / (1.0f + expf(-x)); }

__device__ __forceinline__ u16 f2bf_rtne(float f) {
    u32 u = __float_as_uint(f);
    u = (u + 0x7FFFu + ((u >> 16) & 1u)) >> 16;
    return (u16)u;
}

// ---------------------------------------------------------------------------
// K0: zero the recurrent state
__global__ void k_init(float* __restrict__ h, float* __restrict__ c,
                       float* __restrict__ att) {
    int i = blockIdx.x * 256 + threadIdx.x;
    if (i < BB * HH) { h[i] = 0.f; c[i] = 0.f; }
    if (i < BB * AA) att[i] = 0.f;
}

// ---------------------------------------------------------------------------
// K-cvtswz: W_ih f32 -> bf16 in MFMA A-fragment order.
// Wf[m][kb][l][j]: lane l of tile (m,kb) holds A[row=m*16+(l&15)][k=kb*32+(l>>4)*8+j].
// Writes are perfectly coalesced (16B/thread contiguous); reads consume full
// 128B lines of 16-row panels. K range [IND, INDP) zero-padded.
__global__ __launch_bounds__(256)
void k_cvtswz(const float* __restrict__ W, u16* __restrict__ Wf) {
    const size_t idx = (size_t)blockIdx.x * 256 + threadIdx.x;  // < 256*NKB*64
    const int l = (int)(idx & 63);
    const size_t mkb = idx >> 6;               // m*NKB + kb
    const int kb = (int)(mkb % NKB);
    const int m = (int)(mkb / NKB);
    const int row = m * 16 + (l & 15);
    const int k0 = kb * 32 + ((l >> 4) << 3);
    union { u16 s[8]; u32x4 v; } pk;
    if (k0 + 8 <= IND) {
        const float* src = W + (size_t)row * IND + k0;
        float4 a = *(const float4*)src;
        float4 b = *(const float4*)(src + 4);
        pk.s[0] = f2bf_rtne(a.x); pk.s[1] = f2bf_rtne(a.y);
        pk.s[2] = f2bf_rtne(a.z); pk.s[3] = f2bf_rtne(a.w);
        pk.s[4] = f2bf_rtne(b.x); pk.s[5] = f2bf_rtne(b.y);
        pk.s[6] = f2bf_rtne(b.z); pk.s[7] = f2bf_rtne(b.w);
    } else {
#pragma unroll
        for (int j = 0; j < 8; ++j) {
            const int k = k0 + j;
            pk.s[j] = (k < IND) ? f2bf_rtne(W[(size_t)row * IND + k]) : (u16)0;
        }
    }
    *(u32x4*)(Wf + idx * 8) = pk.v;
}

// ---------------------------------------------------------------------------
// K-prep (per step): build B fragments Bf[kb][l][j] (bf16):
// lane l holds B[k=kb*32+(l>>4)*8+j][col=l&15]; col 0..7 = batch (gated input),
// col 8..15 = zero; k in [IND, INDP) = zero.
__global__ __launch_bounds__(256)
void k_prep(const float* __restrict__ x, const float* __restrict__ masks,
            const float* __restrict__ att, u16* __restrict__ Bf, int t) {
    const int idx = blockIdx.x * 256 + threadIdx.x;
    if (idx >= NKB * 64) return;
    const int kb = idx >> 6, l = idx & 63;
    const int col = l & 15;
    const int k0 = kb * 32 + ((l >> 4) << 3);
    union { u16 s[8]; u32x4 v; } pk;
    if (col >= 8 || k0 >= IND) {
        pk.v = u32x4{0u, 0u, 0u, 0u};
    } else if (k0 + 8 <= INX) {  // pure x region (chunks never straddle INX)
        const float* xp = x + ((size_t)col * TT + t) * INX + k0;
        float4 v0 = *(const float4*)xp;
        float4 v1 = *(const float4*)(xp + 4);
        const float am = att[col * AA + (k0 >> 6)];
        pk.s[0] = f2bf_rtne(v0.x * am); pk.s[1] = f2bf_rtne(v0.y * am);
        pk.s[2] = f2bf_rtne(v0.z * am); pk.s[3] = f2bf_rtne(v0.w * am);
        pk.s[4] = f2bf_rtne(v1.x * am); pk.s[5] = f2bf_rtne(v1.y * am);
        pk.s[6] = f2bf_rtne(v1.z * am); pk.s[7] = f2bf_rtne(v1.w * am);
    } else {
#pragma unroll
        for (int j = 0; j < 8; ++j) {
            const int k = k0 + j;
            float v = 0.f;
            if (k < INX)
                v = x[((size_t)col * TT + t) * INX + k] * att[col * AA + (k >> 6)];
            else if (k < IND)
                v = masks[((size_t)col * TT + t) * AA + (k - INX)];
            pk.s[j] = f2bf_rtne(v);
        }
    }
    *(u32x4*)(Bf + (size_t)kb * 512 + l * 8) = pk.v;
}

// ---------------------------------------------------------------------------
// K-gemm: gates[b][g] = bias + sum_k Wf[g][k] * Bf[k][b] via MFMA 16x16x32.
// 256 blocks (one per 16-row M-tile) x 8 waves (each covers NKB/8 K-blocks).
__global__ __launch_bounds__(512)
void k_gemm(const u16* __restrict__ Wf, const u16* __restrict__ Bf,
            const float* __restrict__ bih, const float* __restrict__ bhh,
            float* __restrict__ gates) {
    const int m = blockIdx.x;
    const int w = threadIdx.x >> 6;
    const int l = threadIdx.x & 63;
    const int kb0 = w * KPW;
    const int kb1 = min(kb0 + KPW, NKB);

    const u16* pa = Wf + ((size_t)((size_t)m * NKB + kb0) * 64 + l) * 8;
    const u16* pb = Bf + (size_t)kb0 * 512 + l * 8;

    f32x4 acc = {0.f, 0.f, 0.f, 0.f};
    int kb = kb0;
    for (; kb + 4 <= kb1; kb += 4) {
        s16x8 a0 = __builtin_nontemporal_load((const s16x8*)(pa));
        s16x8 a1 = __builtin_nontemporal_load((const s16x8*)(pa + 512));
        s16x8 a2 = __builtin_nontemporal_load((const s16x8*)(pa + 1024));
        s16x8 a3 = __builtin_nontemporal_load((const s16x8*)(pa + 1536));
        s16x8 b0 = *(const s16x8*)(pb);
        s16x8 b1 = *(const s16x8*)(pb + 512);
        s16x8 b2 = *(const s16x8*)(pb + 1024);
        s16x8 b3 = *(const s16x8*)(pb + 1536);
        acc = __builtin_amdgcn_mfma_f32_16x16x32_bf16(a0, b0, acc, 0, 0, 0);
        acc = __builtin_amdgcn_mfma_f32_16x16x32_bf16(a1, b1, acc, 0, 0, 0);
        acc = __builtin_amdgcn_mfma_f32_16x16x32_bf16(a2, b2, acc, 0, 0, 0);
        acc = __builtin_amdgcn_mfma_f32_16x16x32_bf16(a3, b3, acc, 0, 0, 0);
        pa += 2048; pb += 2048;
    }
    for (; kb < kb1; ++kb) {
        s16x8 a0 = __builtin_nontemporal_load((const s16x8*)(pa));
        s16x8 b0 = *(const s16x8*)(pb);
        acc = __builtin_amdgcn_mfma_f32_16x16x32_bf16(a0, b0, acc, 0, 0, 0);
        pa += 512; pb += 512;
    }

    // Reduce 8 partial 16x16 tiles. C layout: col=lane&15, row=(lane>>4)*4+i.
    __shared__ float lds[8][16][16];
#pragma unroll
    for (int i = 0; i < 4; ++i) lds[w][((l >> 4) << 2) + i][l & 15] = acc[i];
    __syncthreads();
    if (threadIdx.x < 256) {
        const int row = threadIdx.x >> 4, coln = threadIdx.x & 15;
        float s = 0.f;
#pragma unroll
        for (int ww = 0; ww < 8; ++ww) s += lds[ww][row][coln];
        if (coln < 8) {
            const int g = m * 16 + row;
            gates[coln * G4 + g] = s + bih[g] + bhh[g];
        }
    }
}

// ---------------------------------------------------------------------------
// K-hh: gates[b][g] += sum_j Whh[g][j] * h[b][j]  (f32 for precision)
__global__ __launch_bounds__(256)
void k_hh(const float* __restrict__ Whh, const float* __restrict__ h,
          float* __restrict__ gates) {
    const int tid = threadIdx.x;
    const int g0 = blockIdx.x * 8;
    float acc[8][8];
#pragma unroll
    for (int r = 0; r < 8; ++r)
#pragma unroll
        for (int b = 0; b < 8; ++b) acc[r][b] = 0.f;
    for (int j = tid; j < HH; j += 256) {
        float hv[8];
#pragma unroll
        for (int b = 0; b < 8; ++b) hv[b] = h[b * HH + j];
#pragma unroll
        for (int r = 0; r < 8; ++r) {
            const float w = Whh[(size_t)(g0 + r) * HH + j];
#pragma unroll
            for (int b = 0; b < 8; ++b) acc[r][b] = fmaf(w, hv[b], acc[r][b]);
        }
    }
#pragma unroll
    for (int r = 0; r < 8; ++r)
#pragma unroll
        for (int b = 0; b < 8; ++b) {
            float v = acc[r][b];
            for (int off = 32; off; off >>= 1) v += __shfl_down(v, off, 64);
            acc[r][b] = v;
        }
    __shared__ float red[4][8][8];
    const int wave = tid >> 6, lane = tid & 63;
    if (lane == 0) {
#pragma unroll
        for (int r = 0; r < 8; ++r)
#pragma unroll
            for (int b = 0; b < 8; ++b) red[wave][r][b] = acc[r][b];
    }
    __syncthreads();
    if (tid < 64) {
        const int r = tid >> 3, b = tid & 7;
        gates[b * G4 + g0 + r] +=
            red[0][r][b] + red[1][r][b] + red[2][r][b] + red[3][r][b];
    }
}

// ---------------------------------------------------------------------------
// K-cell: pointwise LSTM update
__global__ void k_cell(const float* __restrict__ gates, float* __restrict__ c,
                       float* __restrict__ h, float* __restrict__ hrelu) {
    int idx = blockIdx.x * 256 + threadIdx.x;
    if (idx >= BB * HH) return;
    const int b = idx >> 10, j = idx & (HH - 1);
    const float* gb = gates + b * G4;
    float ig = sigf(gb[j]);
    float fg = sigf(gb[HH + j]);
    float gg = tanhf(gb[2 * HH + j]);
    float og = sigf(gb[3 * HH + j]);
    float cn = fg * c[idx] + ig * gg;
    float hn = og * tanhf(cn);
    c[idx] = cn;
    h[idx] = hn;
    hrelu[idx] = fmaxf(hn, 0.f);
}

// ---------------------------------------------------------------------------
// K-attout: att_new = sigmoid(hrelu @ W_att.T + b_att); out_t = sigmoid(hrelu @ W_out.T + b_out)
__global__ __launch_bounds__(256)
void k_attout(const float* __restrict__ hrelu,
              const float* __restrict__ Watt, const float* __restrict__ batt,
              const float* __restrict__ Wout, const float* __restrict__ bout,
              float* __restrict__ att, float* __restrict__ out, int t) {
    const int wid = blockIdx.x * 4 + (threadIdx.x >> 6);
    const int lane = threadIdx.x & 63;
    if (wid >= 2 * AA) return;
    const bool isAtt = wid < AA;
    const int row = isAtt ? wid : wid - AA;
    const float* W = isAtt ? Watt : Wout;

    float acc[8];
#pragma unroll
    for (int b = 0; b < 8; ++b) acc[b] = 0.f;
    for (int j = lane; j < HH; j += 64) {
        const float w = W[(size_t)row * HH + j];
#pragma unroll
        for (int b = 0; b < 8; ++b) acc[b] = fmaf(w, hrelu[b * HH + j], acc[b]);
    }
#pragma unroll
    for (int b = 0; b < 8; ++b) {
        float v = acc[b];
        for (int off = 32; off; off >>= 1) v += __shfl_xor(v, off, 64);
        acc[b] = v;
    }
    if (lane < 8) {
        const int b = lane;
        if (isAtt)
            att[b * AA + row] = sigf(acc[b] + batt[row]);
        else
            out[((size_t)b * TT + t) * AA + row] = sigf(acc[b] + bout[row]);
    }
}

// ---------------------------------------------------------------------------
// Fallback f32 path (validated round 1) if ws is too small for bf16 weights.
__global__ __launch_bounds__(256, 2)
void k_gates_f32(const float* __restrict__ x, const float* __restrict__ masks,
                 const float* __restrict__ Wih, const float* __restrict__ Whh,
                 const float* __restrict__ bih, const float* __restrict__ bhh,
                 const float* __restrict__ h, const float* __restrict__ att,
                 float* __restrict__ gates, int t) {
    __shared__ float att_s[BB * AA];
    const int tid = threadIdx.x;
    for (int i = tid; i < BB * AA; i += 256) att_s[i] = att[i];
    __syncthreads();
    const int g0 = blockIdx.x * 8;
    float acc[8][8];
#pragma unroll
    for (int r = 0; r < 8; ++r)
#pragma unroll
        for (int b = 0; b < 8; ++b) acc[r][b] = 0.f;
    const float* xb = x + (size_t)t * INX;
    for (int k = tid; k < INX; k += 256) {
        const int ij = k >> 6;
        float xa[8];
#pragma unroll
        for (int b = 0; b < 8; ++b)
            xa[b] = xb[(size_t)b * TT * INX + k] * att_s[b * AA + ij];
#pragma unroll
        for (int r = 0; r < 8; ++r) {
            float w = __builtin_nontemporal_load(&Wih[(size_t)(g0 + r) * IND + k]);
#pragma unroll
            for (int b = 0; b < 8; ++b) acc[r][b] = fmaf(w, xa[b], acc[r][b]);
        }
    }
    const float* mb = masks + (size_t)t * AA;
    for (int k = tid; k < AA; k += 256) {
        float mv[8];
#pragma unroll
        for (int b = 0; b < 8; ++b) mv[b] = mb[(size_t)b * TT * AA + k];
#pragma unroll
        for (int r = 0; r < 8; ++r) {
            float w = __builtin_nontemporal_load(&Wih[(size_t)(g0 + r) * IND + INX + k]);
#pragma unroll
            for (int b = 0; b < 8; ++b) acc[r][b] = fmaf(w, mv[b], acc[r][b]);
        }
    }
    for (int j = tid; j < HH; j += 256) {
        float hv[8];
#pragma unroll
        for (int b = 0; b < 8; ++b) hv[b] = h[b * HH + j];
#pragma unroll
        for (int r = 0; r < 8; ++r) {
            float w = Whh[(size_t)(g0 + r) * HH + j];
#pragma unroll
            for (int b = 0; b < 8; ++b) acc[r][b] = fmaf(w, hv[b], acc[r][b]);
        }
    }
#pragma unroll
    for (int r = 0; r < 8; ++r)
#pragma unroll
        for (int b = 0; b < 8; ++b) {
            float v = acc[r][b];
            for (int off = 32; off; off >>= 1) v += __shfl_down(v, off, 64);
            acc[r][b] = v;
        }
    __shared__ float red[4][8][8];
    const int wave = tid >> 6, lane = tid & 63;
    if (lane == 0) {
#pragma unroll
        for (int r = 0; r < 8; ++r)
#pragma unroll
            for (int b = 0; b < 8; ++b) red[wave][r][b] = acc[r][b];
    }
    __syncthreads();
    if (tid < 64) {
        const int r = tid >> 3, b = tid & 7;
        const int g = g0 + r;
        float v = red[0][r][b] + red[1][r][b] + red[2][r][b] + red[3][r][b];
        gates[b * G4 + g] = v + bih[g] + bhh[g];
    }
}

// ---------------------------------------------------------------------------
extern "C" void kernel_launch(void* const* d_in, const int* in_sizes, int n_in,
                              void* d_out, int out_size, void* d_ws, size_t ws_size,
                              hipStream_t stream) {
    const float* tensors = (const float*)d_in[0];
    const float* masks   = (const float*)d_in[1];
    const float* Wih     = (const float*)d_in[2];
    const float* Whh     = (const float*)d_in[3];
    const float* bih     = (const float*)d_in[4];
    const float* bhh     = (const float*)d_in[5];
    const float* Watt    = (const float*)d_in[6];
    const float* batt    = (const float*)d_in[7];
    const float* Wout    = (const float*)d_in[8];
    const float* bout    = (const float*)d_in[9];
    float* out = (float*)d_out;

    float* ws    = (float*)d_ws;
    float* h     = ws;                // 8192 f32
    float* c     = h + BB * HH;       // 8192
    float* hrelu = c + BB * HH;       // 8192
    float* att   = hrelu + BB * HH;   // 11552
    float* gates = att + BB * AA;     // 32768
    u16*   Bf    = (u16*)(gates + BB * G4);          // NKB*512 bf16 (3.0 MB)
    u16*   Wf    = Bf + (size_t)NKB * 512;           // 4096*INDP bf16 (769 MB)

    const size_t need = (size_t)(3 * BB * HH + BB * AA + BB * G4) * 4
                      + (size_t)NKB * 512 * 2 + (size_t)G4 * INDP * 2;
    const bool mfma_path = ws_size >= need;

    k_init<<<46, 256, 0, stream>>>(h, c, att);
    if (mfma_path) {
        k_cvtswz<<<NKB * 64, 256, 0, stream>>>(Wih, Wf);
        for (int t = 0; t < TT; ++t) {
            k_prep<<<(NKB * 64 + 255) / 256, 256, 0, stream>>>(tensors, masks,
                                                               att, Bf, t);
            k_gemm<<<256, 512, 0, stream>>>(Wf, Bf, bih, bhh, gates);
            k_hh<<<512, 256, 0, stream>>>(Whh, h, gates);
            k_cell<<<32, 256, 0, stream>>>(gates, c, h, hrelu);
            k_attout<<<722, 256, 0, stream>>>(hrelu, Watt, batt, Wout, bout,
                                              att, out, t);
        }
    } else {
        for (int t = 0; t < TT; ++t) {
            k_gates_f32<<<512, 256, 0, stream>>>(tensors, masks, Wih, Whh, bih,
                                                 bhh, h, att, gates, t);
            k_cell<<<32, 256, 0, stream>>>(gates, c, h, hrelu);
            k_attout<<<722, 256, 0, stream>>>(hrelu, Watt, batt, Wout, bout,
                                              att, out, t);
        }
    }
}